// Round 12
// baseline (355.310 us; speedup 1.0000x reference)
//
#include <hip/hip_runtime.h>
#include <cstdint>

#define MM 524288           // B*N points
#define NSEG 4096           // B*K segments

// ws layout (u32 units) — round-11 layout
#define WS_SCNT   0u
#define WS_CURSOR 4096u
#define WS_OFFS   8192u
#define WS_M1     12288u    // 16 f32
#define WS_SEGF   28688u    // 393216 f32
#define WS_ZSEG   421904u   // 393216 f32
#define WS_SORTED 815120u   // 524288 u32
#define WS_SEG16  1339408u  // 262144 u32 (524288 u16 slot->segment)
#define WS_WSRT   1601552u  // 524288 f32 (w in sorted order)
#define WS_H8     2125840u  // 25165824 u32 (MM*96 bf16 chunks), 16B-aligned
#define WS_PTS    27291664u // 1572864 f32 (normalized pts, PLANAR x|y|z, slot order)
#define WS_END    28864528u

typedef __attribute__((ext_vector_type(8))) short short8;
typedef __attribute__((ext_vector_type(4))) float f32x4;

#define WPAD 104            // padded K-stride (bf16 elems) for transposed weight tiles in LDS

// ---------- helpers ----------
__device__ __forceinline__ unsigned bfr(float x) {   // f32 -> bf16 bits, RTN-even
    unsigned u = __float_as_uint(x);
    return (u + 0x7FFFu + ((u >> 16) & 1u)) >> 16;
}
__device__ __forceinline__ float bf2f(unsigned v) {  // low 16 bits -> f32
    return __uint_as_float(v << 16);
}
union U4S8 { uint4 u; short8 s; };

// ---------- k0: zero scnt + cursor ----------
__global__ void __launch_bounds__(256) k0_init(unsigned* __restrict__ ws)
{
    unsigned i = blockIdx.x * 256u + threadIdx.x;
    if (i < 8192u) ws[i] = 0u;
}

// ---------- k1: per-segment counts (LDS histogram) ----------
__global__ void __launch_bounds__(256) k1_count(
    const int* __restrict__ spidx, unsigned* __restrict__ scnt)
{
    __shared__ unsigned lcnt[512];
    int tid = threadIdx.x;
    for (int j = tid; j < 512; j += 256) lcnt[j] = 0u;
    __syncthreads();
    int base = blockIdx.x * 4096;
    #pragma unroll 4
    for (int it = 0; it < 16; ++it) {
        int p = base + it*256 + tid;
        atomicAdd(&lcnt[spidx[p]], 1u);
    }
    __syncthreads();
    int b = blockIdx.x >> 4;
    for (int j = tid; j < 512; j += 256)
        atomicAdd(&scnt[(b << 9) + j], lcnt[j]);
}

// ---------- k2: scan counts -> offs; W1/b1 moments ----------
__global__ void __launch_bounds__(1024) k2_scan(
    const unsigned* __restrict__ scnt, unsigned* __restrict__ offs,
    const float* __restrict__ W1, const float* __restrict__ b1, float* __restrict__ m1)
{
    __shared__ unsigned sh[1024];
    int t = threadIdx.x;
    unsigned c0 = scnt[t*4+0], c1 = scnt[t*4+1], c2 = scnt[t*4+2], c3 = scnt[t*4+3];
    unsigned tot = c0 + c1 + c2 + c3;
    sh[t] = tot;
    __syncthreads();
    for (int d = 1; d < 1024; d <<= 1) {
        unsigned v = (t >= d) ? sh[t-d] : 0u;
        __syncthreads();
        sh[t] += v;
        __syncthreads();
    }
    unsigned excl = sh[t] - tot;
    offs[t*4+0] = excl;
    offs[t*4+1] = excl + c0;
    offs[t*4+2] = excl + c0 + c1;
    offs[t*4+3] = excl + c0 + c1 + c2;

    if (t == 0) {
        float Sa=0,Sb=0,Sc=0,Sd=0,Saa=0,Sbb=0,Scc=0,Sdd=0,Sab=0,Sac=0,Sad=0,Sbc=0,Sbd=0,Scd=0;
        #pragma unroll 8
        for (int j = 0; j < 96; ++j) {
            float A = W1[j], B2 = W1[96+j], C2 = W1[192+j], D = b1[j];
            Sa+=A; Sb+=B2; Sc+=C2; Sd+=D;
            Saa=fmaf(A,A,Saa); Sbb=fmaf(B2,B2,Sbb); Scc=fmaf(C2,C2,Scc); Sdd=fmaf(D,D,Sdd);
            Sab=fmaf(A,B2,Sab); Sac=fmaf(A,C2,Sac); Sad=fmaf(A,D,Sad);
            Sbc=fmaf(B2,C2,Sbc); Sbd=fmaf(B2,D,Sbd); Scd=fmaf(C2,D,Scd);
        }
        const float inv = 1.f/96.f;
        float Am=Sa*inv, Bm=Sb*inv, Cm=Sc*inv, Dm=Sd*inv;
        m1[0]=Am; m1[1]=Bm; m1[2]=Cm; m1[3]=Dm;
        m1[4]=Saa*inv-Am*Am; m1[5]=Sbb*inv-Bm*Bm; m1[6]=Scc*inv-Cm*Cm; m1[7]=Sdd*inv-Dm*Dm;
        m1[8]=Sab*inv-Am*Bm; m1[9]=Sac*inv-Am*Cm; m1[10]=Sad*inv-Am*Dm;
        m1[11]=Sbc*inv-Bm*Cm; m1[12]=Sbd*inv-Bm*Dm; m1[13]=Scd*inv-Cm*Dm;
    }
}

// ---------- k3: scatter point ids by segment; also slot->segment id ----------
__global__ void __launch_bounds__(256) k3_scatter(
    const int* __restrict__ spidx, const unsigned* __restrict__ offs,
    unsigned* __restrict__ cursor, unsigned* __restrict__ sorted,
    unsigned short* __restrict__ seg16)
{
    __shared__ unsigned lcnt[512];
    __shared__ unsigned gbase[512];
    __shared__ unsigned short rank16[4096];
    int tid = threadIdx.x;
    for (int j = tid; j < 512; j += 256) lcnt[j] = 0u;
    __syncthreads();
    int base = blockIdx.x * 4096;
    #pragma unroll 4
    for (int it = 0; it < 16; ++it) {
        int p = base + it*256 + tid;
        unsigned r = atomicAdd(&lcnt[spidx[p]], 1u);
        rank16[it*256 + tid] = (unsigned short)r;
    }
    __syncthreads();
    int b = blockIdx.x >> 4;
    for (int j = tid; j < 512; j += 256)
        gbase[j] = atomicAdd(&cursor[(b << 9) + j], lcnt[j]);
    __syncthreads();
    #pragma unroll 4
    for (int it = 0; it < 16; ++it) {
        int p = base + it*256 + tid;
        int sl = spidx[p];
        int s = (b << 9) + sl;
        unsigned pos = offs[s] + gbase[sl] + (unsigned)rank16[it*256 + tid];
        sorted[pos] = (unsigned)p;
        seg16[pos] = (unsigned short)s;
    }
}

// ---------- k3b: per-segment xyz stats; write normalized pts (planar, slot order) ----------
__global__ void __launch_bounds__(128) k3b_stats(
    const float* __restrict__ xyz, const unsigned* __restrict__ sorted,
    const unsigned* __restrict__ offs, const unsigned* __restrict__ scnt,
    float* __restrict__ pts)
{
    int s = blockIdx.x, tid = threadIdx.x;
    unsigned cnt = scnt[s], off = offs[s];
    float mnx=INFINITY, mny=INFINITY, mnz=INFINITY;
    float mxx=-INFINITY, mxy=-INFINITY, mxz=-INFINITY;
    float smx=0.f, smy=0.f, smz=0.f;
    for (unsigned r = tid; r < cnt; r += 128) {
        unsigned p = sorted[off + r];
        float x = xyz[3*p], y = xyz[3*p+1], z = xyz[3*p+2];
        mnx = fminf(mnx, x); mny = fminf(mny, y); mnz = fminf(mnz, z);
        mxx = fmaxf(mxx, x); mxy = fmaxf(mxy, y); mxz = fmaxf(mxz, z);
        smx += x; smy += y; smz += z;
    }
    #pragma unroll
    for (int m = 1; m < 64; m <<= 1) {
        mnx = fminf(mnx, __shfl_xor(mnx, m)); mny = fminf(mny, __shfl_xor(mny, m));
        mnz = fminf(mnz, __shfl_xor(mnz, m));
        mxx = fmaxf(mxx, __shfl_xor(mxx, m)); mxy = fmaxf(mxy, __shfl_xor(mxy, m));
        mxz = fmaxf(mxz, __shfl_xor(mxz, m));
        smx += __shfl_xor(smx, m); smy += __shfl_xor(smy, m); smz += __shfl_xor(smz, m);
    }
    __shared__ float cw[2][9];
    __shared__ float cd[4];    // cx, cy, cz, dinv
    if ((tid & 63) == 0) {
        int w = tid >> 6;
        cw[w][0]=mnx; cw[w][1]=mny; cw[w][2]=mnz;
        cw[w][3]=mxx; cw[w][4]=mxy; cw[w][5]=mxz;
        cw[w][6]=smx; cw[w][7]=smy; cw[w][8]=smz;
    }
    __syncthreads();
    if (tid == 0) {
        float a0=fminf(cw[0][0],cw[1][0]), a1=fminf(cw[0][1],cw[1][1]), a2=fminf(cw[0][2],cw[1][2]);
        float b0=fmaxf(cw[0][3],cw[1][3]), b1=fmaxf(cw[0][4],cw[1][4]), b2=fmaxf(cw[0][5],cw[1][5]);
        float s0=cw[0][6]+cw[1][6], s1=cw[0][7]+cw[1][7], s2=cw[0][8]+cw[1][8];
        float cc = fmaxf((float)cnt, 1.f);
        float dm = fmaxf(fmaxf(b0-a0, b1-a1), b2-a2);
        cd[0] = s0/cc; cd[1] = s1/cc; cd[2] = s2/cc;
        cd[3] = 1.f / (dm + 0.01f);
    }
    __syncthreads();
    float cx = cd[0], cy = cd[1], cz = cd[2], dinv = cd[3];
    for (unsigned r = tid; r < cnt; r += 128) {
        unsigned p = sorted[off + r];     // L2-hot from pass 1
        unsigned o = off + r;
        pts[o]              = (xyz[3*p+0] - cx) * dinv;
        pts[MM + o]         = (xyz[3*p+1] - cy) * dinv;
        pts[2u*MM + o]      = (xyz[3*p+2] - cz) * dinv;
    }
}

// ---------- kTA: MLP1 via MFMA -> h8 (bf16 chunks, slot order) ----------
__global__ void __launch_bounds__(256) kTA(
    const float* __restrict__ pts,
    const float* __restrict__ W1, const float* __restrict__ b1,
    const float* __restrict__ g1, const float* __restrict__ be1,
    const float* __restrict__ m1,
    const float* __restrict__ W2, const float* __restrict__ b2,
    const float* __restrict__ g2, const float* __restrict__ be2,
    uint4* __restrict__ h8)
{
    __shared__ unsigned short wT[96*WPAD];   // W2 transposed, bf16
    __shared__ float pw8[96*8];              // per-row: W1r0,W1r1,W1r2,b1 | g1,be1,0,0
    __shared__ float prm[3*96];              // b2,g2,be2
    __shared__ float mcl[14];
    int tid = threadIdx.x;
    #pragma unroll 4
    for (int it = 0; it < 36; ++it) {
        int e = it*256 + tid;
        int i = e / 96, j = e - i*96;
        wT[j*WPAD + i] = (unsigned short)bfr(W2[e]);
    }
    if (tid < 96) {
        pw8[tid*8+0] = W1[tid]; pw8[tid*8+1] = W1[96+tid]; pw8[tid*8+2] = W1[192+tid];
        pw8[tid*8+3] = b1[tid]; pw8[tid*8+4] = g1[tid];    pw8[tid*8+5] = be1[tid];
        pw8[tid*8+6] = 0.f;     pw8[tid*8+7] = 0.f;
        prm[tid] = b2[tid]; prm[96+tid] = g2[tid]; prm[192+tid] = be2[tid];
    }
    if (tid < 14) mcl[tid] = m1[tid];
    __syncthreads();

    int lane = tid & 63, w = tid >> 6;
    int pcol = lane & 15, g = lane >> 4;
    size_t slot0 = (size_t)blockIdx.x * 256 + w*64 + pcol;
    const f32x4* pwv = (const f32x4*)pw8;

    #pragma unroll 1
    for (int t = 0; t < 4; ++t) {
        size_t slot = slot0 + (size_t)t * 16;
        float px = pts[slot];
        float py = pts[(size_t)MM + slot];
        float pz = pts[2u*(size_t)MM + slot];

        float mu = fmaf(px, mcl[0], fmaf(py, mcl[1], fmaf(pz, mcl[2], mcl[3])));
        float var = fmaf(px*px, mcl[4], fmaf(py*py, mcl[5], fmaf(pz*pz, mcl[6], mcl[7])));
        var = fmaf(2.f*px*py, mcl[8],  var);
        var = fmaf(2.f*px*pz, mcl[9],  var);
        var = fmaf(2.f*px,    mcl[10], var);
        var = fmaf(2.f*py*pz, mcl[11], var);
        var = fmaf(2.f*py,    mcl[12], var);
        var = fmaf(2.f*pz,    mcl[13], var);
        float rs = rsqrtf(var + 1e-5f);

        f32x4 acc[6];
        #pragma unroll
        for (int nt = 0; nt < 6; ++nt) acc[nt] = (f32x4){0.f,0.f,0.f,0.f};

        #pragma unroll
        for (int ks = 0; ks < 3; ++ks) {
            U4S8 bu;
            unsigned vv[4];
            #pragma unroll
            for (int e2 = 0; e2 < 4; ++e2) {
                int i0 = ks*32 + g*8 + e2*2;
                f32x4 lo0 = pwv[i0*2],     hi0 = pwv[i0*2+1];
                f32x4 lo1 = pwv[(i0+1)*2], hi1 = pwv[(i0+1)*2+1];
                float ta = fmaf(px, lo0[0], fmaf(py, lo0[1], fmaf(pz, lo0[2], lo0[3])));
                ta = fmaxf(fmaf((ta - mu) * rs, hi0[0], hi0[1]), 0.f);
                float tb = fmaf(px, lo1[0], fmaf(py, lo1[1], fmaf(pz, lo1[2], lo1[3])));
                tb = fmaxf(fmaf((tb - mu) * rs, hi1[0], hi1[1]), 0.f);
                vv[e2] = bfr(ta) | (bfr(tb) << 16);
            }
            bu.u.x = vv[0]; bu.u.y = vv[1]; bu.u.z = vv[2]; bu.u.w = vv[3];
            #pragma unroll
            for (int nt = 0; nt < 6; ++nt) {
                const short8 aF = *(const short8*)&wT[(nt*16 + pcol)*WPAD + ks*32 + g*8];
                acc[nt] = __builtin_amdgcn_mfma_f32_16x16x32_bf16(aF, bu.s, acc[nt], 0, 0, 0);
            }
        }

        float sum = 0.f, sq = 0.f;
        #pragma unroll
        for (int nt = 0; nt < 6; ++nt) {
            f32x4 bv = *(const f32x4*)&prm[nt*16 + g*4];
            #pragma unroll
            for (int r = 0; r < 4; ++r) {
                float v = acc[nt][r] + bv[r];
                acc[nt][r] = v;
                sum += v;
                sq = fmaf(v, v, sq);
            }
        }
        sum += __shfl_xor(sum, 16); sum += __shfl_xor(sum, 32);
        sq  += __shfl_xor(sq, 16);  sq  += __shfl_xor(sq, 32);
        float muh = sum * (1.f/96.f);
        float rsh = rsqrtf(sq * (1.f/96.f) - muh*muh + 1e-5f);

        #pragma unroll
        for (int nt = 0; nt < 6; ++nt) {
            f32x4 gv  = *(const f32x4*)&prm[96  + nt*16 + g*4];
            f32x4 bev = *(const f32x4*)&prm[192 + nt*16 + g*4];
            float o0 = fmaf((acc[nt][0]-muh)*rsh, gv[0], bev[0]);
            float o1 = fmaf((acc[nt][1]-muh)*rsh, gv[1], bev[1]);
            float o2 = fmaf((acc[nt][2]-muh)*rsh, gv[2], bev[2]);
            float o3 = fmaf((acc[nt][3]-muh)*rsh, gv[3], bev[3]);
            uint2 st;
            st.x = bfr(o0) | (bfr(o1) << 16);
            st.y = bfr(o2) | (bfr(o3) << 16);
            int j0 = nt*16 + g*4;
            size_t q = (size_t)(nt*2 + (g >> 1));
            *(uint2*)((char*)h8 + (q*MM + slot)*16 + (size_t)(j0 & 7)*2) = st;
        }
    }
}

// ---------- kB: per-segment column max (double-buffered LDS staging) + zseg ----------
__global__ void __launch_bounds__(192) kB_seg(
    const uint4* __restrict__ h8,
    const unsigned* __restrict__ offs, const unsigned* __restrict__ scnt,
    const float* __restrict__ W3, const float* __restrict__ b3,
    float* __restrict__ segf, float* __restrict__ zseg)
{
    __shared__ uint4 st[2][16][13];
    __shared__ float lseg[96];
    int s = blockIdx.x, tid = threadIdx.x;
    unsigned cnt = scnt[s], off = offs[s];
    int r = tid & 15, q = tid >> 4;        // q < 12 for tid < 192
    float mx = -INFINITY;

    if (q < 12) {
        uint4 v = make_uint4(0xFF80FF80u, 0xFF80FF80u, 0xFF80FF80u, 0xFF80FF80u);
        if ((unsigned)r < cnt) v = h8[(size_t)q * MM + off + r];
        st[0][r][q] = v;
    }
    __syncthreads();

    for (unsigned base = 0; base < cnt; base += 16) {
        int cur = (int)((base >> 4) & 1u);
        unsigned nb = base + 16;
        if (nb < cnt && q < 12) {
            uint4 v = make_uint4(0xFF80FF80u, 0xFF80FF80u, 0xFF80FF80u, 0xFF80FF80u);
            if (nb + (unsigned)r < cnt) v = h8[(size_t)q * MM + off + nb + r];
            st[cur ^ 1][r][q] = v;
        }
        if (tid < 96) {
            int qj = tid >> 3, ej = tid & 7;
            #pragma unroll
            for (int rr = 0; rr < 16; ++rr) {
                const unsigned short* hp = (const unsigned short*)&st[cur][rr][qj];
                mx = fmaxf(mx, bf2f(hp[ej]));
            }
        }
        __syncthreads();
    }
    if (tid < 96) { segf[(size_t)s*96 + tid] = mx; lseg[tid] = mx; }
    __syncthreads();
    if (tid < 96) {
        float acc = b3[tid];
        #pragma unroll 4
        for (int i = 0; i < 96; ++i)
            acc = fmaf(lseg[i], W3[(size_t)(96+i)*96 + tid], acc);
        zseg[(size_t)s*96 + tid] = acc;
    }
}

// ---------- kC: recompute h from pts, wave-local LDS transpose, MLP2 via MFMA -> w ----------
__global__ void __launch_bounds__(256) kC_rec(
    const float* __restrict__ pts, const float* __restrict__ zseg,
    const unsigned short* __restrict__ seg16, const unsigned* __restrict__ sorted,
    const float* __restrict__ W1, const float* __restrict__ b1,
    const float* __restrict__ g1, const float* __restrict__ be1,
    const float* __restrict__ m1,
    const float* __restrict__ W2, const float* __restrict__ b2,
    const float* __restrict__ g2, const float* __restrict__ be2,
    const float* __restrict__ W3, const float* __restrict__ g3,
    const float* __restrict__ be3, const float* __restrict__ W4,
    float* __restrict__ w_nat, float* __restrict__ w_srt)
{
    __shared__ unsigned short wT2[96*WPAD];   // W2^T bf16 (for h)
    __shared__ unsigned short wT3[96*WPAD];   // W3a^T bf16 (for MLP2)
    __shared__ float pw8[96*8];
    __shared__ float prm2[3*96];              // b2,g2,be2
    __shared__ float prm3[3*96];              // g3,be3,W4
    __shared__ float mcl[14];
    __shared__ __align__(16) unsigned short tbuf[4][16*104];  // per-wave transpose buffer
    int tid = threadIdx.x;
    #pragma unroll 4
    for (int it = 0; it < 36; ++it) {
        int e = it*256 + tid;
        int i = e / 96, j = e - i*96;
        wT2[j*WPAD + i] = (unsigned short)bfr(W2[e]);
        wT3[j*WPAD + i] = (unsigned short)bfr(W3[e]);   // W3a = first 96 rows
    }
    if (tid < 96) {
        pw8[tid*8+0] = W1[tid]; pw8[tid*8+1] = W1[96+tid]; pw8[tid*8+2] = W1[192+tid];
        pw8[tid*8+3] = b1[tid]; pw8[tid*8+4] = g1[tid];    pw8[tid*8+5] = be1[tid];
        pw8[tid*8+6] = 0.f;     pw8[tid*8+7] = 0.f;
        prm2[tid] = b2[tid]; prm2[96+tid] = g2[tid]; prm2[192+tid] = be2[tid];
        prm3[tid] = g3[tid]; prm3[96+tid] = be3[tid]; prm3[192+tid] = W4[tid];
    }
    if (tid < 14) mcl[tid] = m1[tid];
    __syncthreads();

    int lane = tid & 63, w = tid >> 6;
    int pcol = lane & 15, g = lane >> 4;
    size_t slot0 = (size_t)blockIdx.x * 256 + w*64 + pcol;
    const f32x4* pwv = (const f32x4*)pw8;
    unsigned short* tb = &tbuf[w][0];

    #pragma unroll 1
    for (int t = 0; t < 4; ++t) {
        size_t slot = slot0 + (size_t)t * 16;
        float px = pts[slot];
        float py = pts[(size_t)MM + slot];
        float pz = pts[2u*(size_t)MM + slot];

        float mu = fmaf(px, mcl[0], fmaf(py, mcl[1], fmaf(pz, mcl[2], mcl[3])));
        float var = fmaf(px*px, mcl[4], fmaf(py*py, mcl[5], fmaf(pz*pz, mcl[6], mcl[7])));
        var = fmaf(2.f*px*py, mcl[8],  var);
        var = fmaf(2.f*px*pz, mcl[9],  var);
        var = fmaf(2.f*px,    mcl[10], var);
        var = fmaf(2.f*py*pz, mcl[11], var);
        var = fmaf(2.f*py,    mcl[12], var);
        var = fmaf(2.f*pz,    mcl[13], var);
        float rs = rsqrtf(var + 1e-5f);

        f32x4 acc[6];
        #pragma unroll
        for (int nt = 0; nt < 6; ++nt) acc[nt] = (f32x4){0.f,0.f,0.f,0.f};

        #pragma unroll
        for (int ks = 0; ks < 3; ++ks) {
            U4S8 bu;
            unsigned vv[4];
            #pragma unroll
            for (int e2 = 0; e2 < 4; ++e2) {
                int i0 = ks*32 + g*8 + e2*2;
                f32x4 lo0 = pwv[i0*2],     hi0 = pwv[i0*2+1];
                f32x4 lo1 = pwv[(i0+1)*2], hi1 = pwv[(i0+1)*2+1];
                float ta = fmaf(px, lo0[0], fmaf(py, lo0[1], fmaf(pz, lo0[2], lo0[3])));
                ta = fmaxf(fmaf((ta - mu) * rs, hi0[0], hi0[1]), 0.f);
                float tb2 = fmaf(px, lo1[0], fmaf(py, lo1[1], fmaf(pz, lo1[2], lo1[3])));
                tb2 = fmaxf(fmaf((tb2 - mu) * rs, hi1[0], hi1[1]), 0.f);
                vv[e2] = bfr(ta) | (bfr(tb2) << 16);
            }
            bu.u.x = vv[0]; bu.u.y = vv[1]; bu.u.z = vv[2]; bu.u.w = vv[3];
            #pragma unroll
            for (int nt = 0; nt < 6; ++nt) {
                const short8 aF = *(const short8*)&wT2[(nt*16 + pcol)*WPAD + ks*32 + g*8];
                acc[nt] = __builtin_amdgcn_mfma_f32_16x16x32_bf16(aF, bu.s, acc[nt], 0, 0, 0);
            }
        }

        // + b2, LN2 -> h (in acc, C/D layout)
        float sum = 0.f, sq = 0.f;
        #pragma unroll
        for (int nt = 0; nt < 6; ++nt) {
            f32x4 bv = *(const f32x4*)&prm2[nt*16 + g*4];
            #pragma unroll
            for (int r = 0; r < 4; ++r) {
                float v = acc[nt][r] + bv[r];
                acc[nt][r] = v;
                sum += v;
                sq = fmaf(v, v, sq);
            }
        }
        sum += __shfl_xor(sum, 16); sum += __shfl_xor(sum, 32);
        sq  += __shfl_xor(sq, 16);  sq  += __shfl_xor(sq, 32);
        float muh = sum * (1.f/96.f);
        float rsh = rsqrtf(sq * (1.f/96.f) - muh*muh + 1e-5f);

        // pack h to bf16, wave-local LDS transpose (C/D layout -> B-fragment layout)
        #pragma unroll
        for (int nt = 0; nt < 6; ++nt) {
            f32x4 gv  = *(const f32x4*)&prm2[96  + nt*16 + g*4];
            f32x4 bev = *(const f32x4*)&prm2[192 + nt*16 + g*4];
            float o0 = fmaf((acc[nt][0]-muh)*rsh, gv[0], bev[0]);
            float o1 = fmaf((acc[nt][1]-muh)*rsh, gv[1], bev[1]);
            float o2 = fmaf((acc[nt][2]-muh)*rsh, gv[2], bev[2]);
            float o3 = fmaf((acc[nt][3]-muh)*rsh, gv[3], bev[3]);
            uint2 st;
            st.x = bfr(o0) | (bfr(o1) << 16);
            st.y = bfr(o2) | (bfr(o3) << 16);
            *(uint2*)&tb[pcol*104 + nt*16 + g*4] = st;
        }
        // tbuf[w] is wave-private: wave-internal LDS ordering (compiler waitcnts) suffices
        U4S8 hb[3];
        #pragma unroll
        for (int ks = 0; ks < 3; ++ks)
            hb[ks].u = *(const uint4*)&tb[pcol*104 + ks*32 + g*8];

        f32x4 a2[6];
        #pragma unroll
        for (int nt = 0; nt < 6; ++nt) a2[nt] = (f32x4){0.f,0.f,0.f,0.f};
        #pragma unroll
        for (int ks = 0; ks < 3; ++ks) {
            #pragma unroll
            for (int nt = 0; nt < 6; ++nt) {
                const short8 aF = *(const short8*)&wT3[(nt*16 + pcol)*WPAD + ks*32 + g*8];
                a2[nt] = __builtin_amdgcn_mfma_f32_16x16x32_bf16(aF, hb[ks].s, a2[nt], 0, 0, 0);
            }
        }

        int s = seg16[slot];
        float sum3 = 0.f, sq3 = 0.f;
        #pragma unroll
        for (int nt = 0; nt < 6; ++nt) {
            f32x4 zs = *(const f32x4*)&zseg[(size_t)s*96 + nt*16 + g*4];
            #pragma unroll
            for (int r = 0; r < 4; ++r) {
                float v = a2[nt][r] + zs[r];
                a2[nt][r] = v;
                sum3 += v;
                sq3 = fmaf(v, v, sq3);
            }
        }
        sum3 += __shfl_xor(sum3, 16); sum3 += __shfl_xor(sum3, 32);
        sq3  += __shfl_xor(sq3, 16);  sq3  += __shfl_xor(sq3, 32);
        float mu3 = sum3 * (1.f/96.f);
        float rs3 = rsqrtf(sq3 * (1.f/96.f) - mu3*mu3 + 1e-5f);

        float tt = 0.f;
        #pragma unroll
        for (int nt = 0; nt < 6; ++nt) {
            f32x4 gv  = *(const f32x4*)&prm3[nt*16 + g*4];
            f32x4 bev = *(const f32x4*)&prm3[96 + nt*16 + g*4];
            f32x4 w4v = *(const f32x4*)&prm3[192 + nt*16 + g*4];
            #pragma unroll
            for (int r = 0; r < 4; ++r) {
                float v = fmaxf(fmaf((a2[nt][r]-mu3)*rs3, gv[r], bev[r]), 0.f);
                tt = fmaf(v, w4v[r], tt);
            }
        }
        tt += __shfl_xor(tt, 16); tt += __shfl_xor(tt, 32);
        if (lane < 16) {
            float wv = 2.f / (1.f + expf(-tt));
            w_srt[slot] = wv;
            w_nat[sorted[slot]] = wv;
        }
    }
}

// ---------- kD: per-segment weighted feat mean + seg (16-deep) ----------
__global__ void __launch_bounds__(128) kD_pool(
    const float* __restrict__ feat, const float* __restrict__ w_srt,
    const unsigned* __restrict__ sorted, const unsigned* __restrict__ offs,
    const unsigned* __restrict__ scnt, const float* __restrict__ segf,
    float* __restrict__ sp_out)
{
    int s = blockIdx.x;
    int c = threadIdx.x;
    unsigned cnt = scnt[s], off = offs[s];
    float acc = 0.f;
    unsigned r = 0;
    for (; r + 16 <= cnt; r += 16) {
        unsigned pp[16]; float ww[16];
        #pragma unroll
        for (int k = 0; k < 16; ++k) {
            pp[k] = sorted[off + r + k];
            ww[k] = w_srt[off + r + k];
        }
        if (c < 96) {
            #pragma unroll
            for (int k = 0; k < 16; ++k)
                acc = fmaf(feat[(size_t)pp[k]*96 + c], ww[k], acc);
        }
    }
    for (; r + 4 <= cnt; r += 4) {
        unsigned pp[4]; float ww[4];
        #pragma unroll
        for (int k = 0; k < 4; ++k) {
            pp[k] = sorted[off + r + k];
            ww[k] = w_srt[off + r + k];
        }
        if (c < 96) {
            #pragma unroll
            for (int k = 0; k < 4; ++k)
                acc = fmaf(feat[(size_t)pp[k]*96 + c], ww[k], acc);
        }
    }
    for (; r < cnt; ++r) {
        unsigned p0 = sorted[off + r];
        float w0 = w_srt[off + r];
        if (c < 96) acc = fmaf(feat[(size_t)p0*96 + c], w0, acc);
    }
    if (c < 96) {
        float cc = fmaxf((float)cnt, 1.f);
        sp_out[(size_t)s*96 + c] = acc / cc + segf[(size_t)s*96 + c];
    }
}

// ---------- launch ----------
extern "C" void kernel_launch(void* const* d_in, const int* in_sizes, int n_in,
                              void* d_out, int out_size, void* d_ws, size_t ws_size,
                              hipStream_t stream)
{
    const float* pts_feat = (const float*)d_in[0];
    const int*   sp_idx   = (const int*)d_in[1];
    const float* xyz      = (const float*)d_in[2];
    const float* W1  = (const float*)d_in[3];
    const float* b1  = (const float*)d_in[4];
    const float* g1  = (const float*)d_in[5];
    const float* be1 = (const float*)d_in[6];
    const float* W2  = (const float*)d_in[7];
    const float* b2  = (const float*)d_in[8];
    const float* g2  = (const float*)d_in[9];
    const float* be2 = (const float*)d_in[10];
    const float* W3  = (const float*)d_in[11];
    const float* b3  = (const float*)d_in[12];
    const float* g3  = (const float*)d_in[13];
    const float* be3 = (const float*)d_in[14];
    const float* W4  = (const float*)d_in[15];

    float* out = (float*)d_out;
    float* sp_out = out;                     // (B*K, 96)
    float* w_out  = out + (size_t)NSEG * 96; // (M,)

    if (ws_size < (size_t)WS_END * 4u) return;

    unsigned* ws32   = (unsigned*)d_ws;
    unsigned* scnt   = ws32 + WS_SCNT;
    unsigned* cursor = ws32 + WS_CURSOR;
    unsigned* offs   = ws32 + WS_OFFS;
    float*    m1     = (float*)(ws32 + WS_M1);
    float*    segf   = (float*)(ws32 + WS_SEGF);
    float*    zseg   = (float*)(ws32 + WS_ZSEG);
    unsigned* sorted = ws32 + WS_SORTED;
    unsigned short* seg16 = (unsigned short*)(ws32 + WS_SEG16);
    float*    w_srt  = (float*)(ws32 + WS_WSRT);
    uint4*    h8     = (uint4*)(ws32 + WS_H8);
    float*    pts    = (float*)(ws32 + WS_PTS);

    k0_init<<<32, 256, 0, stream>>>(ws32);
    k1_count<<<MM/4096, 256, 0, stream>>>(sp_idx, scnt);
    k2_scan<<<1, 1024, 0, stream>>>(scnt, offs, W1, b1, m1);
    k3_scatter<<<MM/4096, 256, 0, stream>>>(sp_idx, offs, cursor, sorted, seg16);
    k3b_stats<<<NSEG, 128, 0, stream>>>(xyz, sorted, offs, scnt, pts);
    kTA<<<MM/256, 256, 0, stream>>>(pts, W1, b1, g1, be1, m1,
        W2, b2, g2, be2, h8);
    kB_seg<<<NSEG, 192, 0, stream>>>(h8, offs, scnt, W3, b3, segf, zseg);
    kC_rec<<<MM/256, 256, 0, stream>>>(pts, zseg, seg16, sorted,
        W1, b1, g1, be1, m1, W2, b2, g2, be2, W3, g3, be3, W4, w_out, w_srt);
    kD_pool<<<NSEG, 128, 0, stream>>>(pts_feat, w_srt, sorted, offs, scnt, segf, sp_out);
}

// Round 13
// 264.300 us; speedup vs baseline: 1.3443x; 1.3443x over previous
//
#include <hip/hip_runtime.h>
#include <cstdint>

#define MM 524288           // B*N points
#define NSEG 4096           // B*K segments

// ws layout (u32 units) — round-11 layout (measured best: 264.7 us)
#define WS_SCNT   0u
#define WS_CURSOR 4096u
#define WS_OFFS   8192u
#define WS_M1     12288u    // 16 f32
#define WS_SEGF   28688u    // 393216 f32
#define WS_ZSEG   421904u   // 393216 f32
#define WS_SORTED 815120u   // 524288 u32
#define WS_SEG16  1339408u  // 262144 u32 (524288 u16 slot->segment)
#define WS_WSRT   1601552u  // 524288 f32 (w in sorted order)
#define WS_H8     2125840u  // 25165824 u32 (MM*96 bf16 chunks), 16B-aligned
#define WS_PTS    27291664u // 1572864 f32 (normalized pts, PLANAR x|y|z, slot order)
#define WS_END    28864528u

typedef __attribute__((ext_vector_type(8))) short short8;
typedef __attribute__((ext_vector_type(4))) float f32x4;

#define WPAD 104            // padded K-stride (bf16 elems) for transposed weight tiles in LDS

// ---------- helpers ----------
__device__ __forceinline__ unsigned bfr(float x) {   // f32 -> bf16 bits, RTN-even
    unsigned u = __float_as_uint(x);
    return (u + 0x7FFFu + ((u >> 16) & 1u)) >> 16;
}
__device__ __forceinline__ float bf2f(unsigned v) {  // low 16 bits -> f32
    return __uint_as_float(v << 16);
}
union U4S8 { uint4 u; short8 s; };

// ---------- k0: zero scnt + cursor ----------
__global__ void __launch_bounds__(256) k0_init(unsigned* __restrict__ ws)
{
    unsigned i = blockIdx.x * 256u + threadIdx.x;
    if (i < 8192u) ws[i] = 0u;
}

// ---------- k1: per-segment counts (LDS histogram) ----------
__global__ void __launch_bounds__(256) k1_count(
    const int* __restrict__ spidx, unsigned* __restrict__ scnt)
{
    __shared__ unsigned lcnt[512];
    int tid = threadIdx.x;
    for (int j = tid; j < 512; j += 256) lcnt[j] = 0u;
    __syncthreads();
    int base = blockIdx.x * 4096;
    #pragma unroll 4
    for (int it = 0; it < 16; ++it) {
        int p = base + it*256 + tid;
        atomicAdd(&lcnt[spidx[p]], 1u);
    }
    __syncthreads();
    int b = blockIdx.x >> 4;
    for (int j = tid; j < 512; j += 256)
        atomicAdd(&scnt[(b << 9) + j], lcnt[j]);
}

// ---------- k2: scan counts -> offs; W1/b1 moments ----------
__global__ void __launch_bounds__(1024) k2_scan(
    const unsigned* __restrict__ scnt, unsigned* __restrict__ offs,
    const float* __restrict__ W1, const float* __restrict__ b1, float* __restrict__ m1)
{
    __shared__ unsigned sh[1024];
    int t = threadIdx.x;
    unsigned c0 = scnt[t*4+0], c1 = scnt[t*4+1], c2 = scnt[t*4+2], c3 = scnt[t*4+3];
    unsigned tot = c0 + c1 + c2 + c3;
    sh[t] = tot;
    __syncthreads();
    for (int d = 1; d < 1024; d <<= 1) {
        unsigned v = (t >= d) ? sh[t-d] : 0u;
        __syncthreads();
        sh[t] += v;
        __syncthreads();
    }
    unsigned excl = sh[t] - tot;
    offs[t*4+0] = excl;
    offs[t*4+1] = excl + c0;
    offs[t*4+2] = excl + c0 + c1;
    offs[t*4+3] = excl + c0 + c1 + c2;

    if (t == 0) {
        float Sa=0,Sb=0,Sc=0,Sd=0,Saa=0,Sbb=0,Scc=0,Sdd=0,Sab=0,Sac=0,Sad=0,Sbc=0,Sbd=0,Scd=0;
        #pragma unroll 8
        for (int j = 0; j < 96; ++j) {
            float A = W1[j], B2 = W1[96+j], C2 = W1[192+j], D = b1[j];
            Sa+=A; Sb+=B2; Sc+=C2; Sd+=D;
            Saa=fmaf(A,A,Saa); Sbb=fmaf(B2,B2,Sbb); Scc=fmaf(C2,C2,Scc); Sdd=fmaf(D,D,Sdd);
            Sab=fmaf(A,B2,Sab); Sac=fmaf(A,C2,Sac); Sad=fmaf(A,D,Sad);
            Sbc=fmaf(B2,C2,Sbc); Sbd=fmaf(B2,D,Sbd); Scd=fmaf(C2,D,Scd);
        }
        const float inv = 1.f/96.f;
        float Am=Sa*inv, Bm=Sb*inv, Cm=Sc*inv, Dm=Sd*inv;
        m1[0]=Am; m1[1]=Bm; m1[2]=Cm; m1[3]=Dm;
        m1[4]=Saa*inv-Am*Am; m1[5]=Sbb*inv-Bm*Bm; m1[6]=Scc*inv-Cm*Cm; m1[7]=Sdd*inv-Dm*Dm;
        m1[8]=Sab*inv-Am*Bm; m1[9]=Sac*inv-Am*Cm; m1[10]=Sad*inv-Am*Dm;
        m1[11]=Sbc*inv-Bm*Cm; m1[12]=Sbd*inv-Bm*Dm; m1[13]=Scd*inv-Cm*Dm;
    }
}

// ---------- k3: scatter point ids by segment; also slot->segment id ----------
__global__ void __launch_bounds__(256) k3_scatter(
    const int* __restrict__ spidx, const unsigned* __restrict__ offs,
    unsigned* __restrict__ cursor, unsigned* __restrict__ sorted,
    unsigned short* __restrict__ seg16)
{
    __shared__ unsigned lcnt[512];
    __shared__ unsigned gbase[512];
    __shared__ unsigned short rank16[4096];
    int tid = threadIdx.x;
    for (int j = tid; j < 512; j += 256) lcnt[j] = 0u;
    __syncthreads();
    int base = blockIdx.x * 4096;
    #pragma unroll 4
    for (int it = 0; it < 16; ++it) {
        int p = base + it*256 + tid;
        unsigned r = atomicAdd(&lcnt[spidx[p]], 1u);
        rank16[it*256 + tid] = (unsigned short)r;
    }
    __syncthreads();
    int b = blockIdx.x >> 4;
    for (int j = tid; j < 512; j += 256)
        gbase[j] = atomicAdd(&cursor[(b << 9) + j], lcnt[j]);
    __syncthreads();
    #pragma unroll 4
    for (int it = 0; it < 16; ++it) {
        int p = base + it*256 + tid;
        int sl = spidx[p];
        int s = (b << 9) + sl;
        unsigned pos = offs[s] + gbase[sl] + (unsigned)rank16[it*256 + tid];
        sorted[pos] = (unsigned)p;
        seg16[pos] = (unsigned short)s;
    }
}

// ---------- k3b: per-segment xyz stats; write normalized pts (planar, slot order) ----------
__global__ void __launch_bounds__(128) k3b_stats(
    const float* __restrict__ xyz, const unsigned* __restrict__ sorted,
    const unsigned* __restrict__ offs, const unsigned* __restrict__ scnt,
    float* __restrict__ pts)
{
    int s = blockIdx.x, tid = threadIdx.x;
    unsigned cnt = scnt[s], off = offs[s];
    float mnx=INFINITY, mny=INFINITY, mnz=INFINITY;
    float mxx=-INFINITY, mxy=-INFINITY, mxz=-INFINITY;
    float smx=0.f, smy=0.f, smz=0.f;
    for (unsigned r = tid; r < cnt; r += 128) {
        unsigned p = sorted[off + r];
        float x = xyz[3*p], y = xyz[3*p+1], z = xyz[3*p+2];
        mnx = fminf(mnx, x); mny = fminf(mny, y); mnz = fminf(mnz, z);
        mxx = fmaxf(mxx, x); mxy = fmaxf(mxy, y); mxz = fmaxf(mxz, z);
        smx += x; smy += y; smz += z;
    }
    #pragma unroll
    for (int m = 1; m < 64; m <<= 1) {
        mnx = fminf(mnx, __shfl_xor(mnx, m)); mny = fminf(mny, __shfl_xor(mny, m));
        mnz = fminf(mnz, __shfl_xor(mnz, m));
        mxx = fmaxf(mxx, __shfl_xor(mxx, m)); mxy = fmaxf(mxy, __shfl_xor(mxy, m));
        mxz = fmaxf(mxz, __shfl_xor(mxz, m));
        smx += __shfl_xor(smx, m); smy += __shfl_xor(smy, m); smz += __shfl_xor(smz, m);
    }
    __shared__ float cw[2][9];
    __shared__ float cd[4];    // cx, cy, cz, dinv
    if ((tid & 63) == 0) {
        int w = tid >> 6;
        cw[w][0]=mnx; cw[w][1]=mny; cw[w][2]=mnz;
        cw[w][3]=mxx; cw[w][4]=mxy; cw[w][5]=mxz;
        cw[w][6]=smx; cw[w][7]=smy; cw[w][8]=smz;
    }
    __syncthreads();
    if (tid == 0) {
        float a0=fminf(cw[0][0],cw[1][0]), a1=fminf(cw[0][1],cw[1][1]), a2=fminf(cw[0][2],cw[1][2]);
        float b0=fmaxf(cw[0][3],cw[1][3]), b1=fmaxf(cw[0][4],cw[1][4]), b2=fmaxf(cw[0][5],cw[1][5]);
        float s0=cw[0][6]+cw[1][6], s1=cw[0][7]+cw[1][7], s2=cw[0][8]+cw[1][8];
        float cc = fmaxf((float)cnt, 1.f);
        float dm = fmaxf(fmaxf(b0-a0, b1-a1), b2-a2);
        cd[0] = s0/cc; cd[1] = s1/cc; cd[2] = s2/cc;
        cd[3] = 1.f / (dm + 0.01f);
    }
    __syncthreads();
    float cx = cd[0], cy = cd[1], cz = cd[2], dinv = cd[3];
    for (unsigned r = tid; r < cnt; r += 128) {
        unsigned p = sorted[off + r];     // L2-hot from pass 1
        unsigned o = off + r;
        pts[o]              = (xyz[3*p+0] - cx) * dinv;
        pts[MM + o]         = (xyz[3*p+1] - cy) * dinv;
        pts[2u*MM + o]      = (xyz[3*p+2] - cz) * dinv;
    }
}

// ---------- kTA: MLP1 via MFMA -> h8 (bf16 chunks, slot order); coalesced pts input ----------
__global__ void __launch_bounds__(256) kTA(
    const float* __restrict__ pts,
    const float* __restrict__ W1, const float* __restrict__ b1,
    const float* __restrict__ g1, const float* __restrict__ be1,
    const float* __restrict__ m1,
    const float* __restrict__ W2, const float* __restrict__ b2,
    const float* __restrict__ g2, const float* __restrict__ be2,
    uint4* __restrict__ h8)
{
    __shared__ unsigned short wT[96*WPAD];   // W2 transposed, bf16
    __shared__ float pw8[96*8];              // per-row: W1r0,W1r1,W1r2,b1 | g1,be1,0,0
    __shared__ float prm[3*96];              // b2,g2,be2
    __shared__ float mcl[14];
    int tid = threadIdx.x;
    #pragma unroll 4
    for (int it = 0; it < 36; ++it) {
        int e = it*256 + tid;
        int i = e / 96, j = e - i*96;
        wT[j*WPAD + i] = (unsigned short)bfr(W2[e]);
    }
    if (tid < 96) {
        pw8[tid*8+0] = W1[tid]; pw8[tid*8+1] = W1[96+tid]; pw8[tid*8+2] = W1[192+tid];
        pw8[tid*8+3] = b1[tid]; pw8[tid*8+4] = g1[tid];    pw8[tid*8+5] = be1[tid];
        pw8[tid*8+6] = 0.f;     pw8[tid*8+7] = 0.f;
        prm[tid] = b2[tid]; prm[96+tid] = g2[tid]; prm[192+tid] = be2[tid];
    }
    if (tid < 14) mcl[tid] = m1[tid];
    __syncthreads();

    int lane = tid & 63, w = tid >> 6;
    int pcol = lane & 15, g = lane >> 4;
    size_t slot0 = (size_t)blockIdx.x * 256 + w*64 + pcol;
    const f32x4* pwv = (const f32x4*)pw8;

    #pragma unroll 1
    for (int t = 0; t < 4; ++t) {
        size_t slot = slot0 + (size_t)t * 16;
        float px = pts[slot];
        float py = pts[(size_t)MM + slot];
        float pz = pts[2u*(size_t)MM + slot];

        float mu = fmaf(px, mcl[0], fmaf(py, mcl[1], fmaf(pz, mcl[2], mcl[3])));
        float var = fmaf(px*px, mcl[4], fmaf(py*py, mcl[5], fmaf(pz*pz, mcl[6], mcl[7])));
        var = fmaf(2.f*px*py, mcl[8],  var);
        var = fmaf(2.f*px*pz, mcl[9],  var);
        var = fmaf(2.f*px,    mcl[10], var);
        var = fmaf(2.f*py*pz, mcl[11], var);
        var = fmaf(2.f*py,    mcl[12], var);
        var = fmaf(2.f*pz,    mcl[13], var);
        float rs = rsqrtf(var + 1e-5f);

        f32x4 acc[6];
        #pragma unroll
        for (int nt = 0; nt < 6; ++nt) acc[nt] = (f32x4){0.f,0.f,0.f,0.f};

        #pragma unroll
        for (int ks = 0; ks < 3; ++ks) {
            U4S8 bu;
            unsigned vv[4];
            #pragma unroll
            for (int e2 = 0; e2 < 4; ++e2) {
                int i0 = ks*32 + g*8 + e2*2;
                f32x4 lo0 = pwv[i0*2],     hi0 = pwv[i0*2+1];
                f32x4 lo1 = pwv[(i0+1)*2], hi1 = pwv[(i0+1)*2+1];
                float ta = fmaf(px, lo0[0], fmaf(py, lo0[1], fmaf(pz, lo0[2], lo0[3])));
                ta = fmaxf(fmaf((ta - mu) * rs, hi0[0], hi0[1]), 0.f);
                float tb = fmaf(px, lo1[0], fmaf(py, lo1[1], fmaf(pz, lo1[2], lo1[3])));
                tb = fmaxf(fmaf((tb - mu) * rs, hi1[0], hi1[1]), 0.f);
                vv[e2] = bfr(ta) | (bfr(tb) << 16);
            }
            bu.u.x = vv[0]; bu.u.y = vv[1]; bu.u.z = vv[2]; bu.u.w = vv[3];
            #pragma unroll
            for (int nt = 0; nt < 6; ++nt) {
                const short8 aF = *(const short8*)&wT[(nt*16 + pcol)*WPAD + ks*32 + g*8];
                acc[nt] = __builtin_amdgcn_mfma_f32_16x16x32_bf16(aF, bu.s, acc[nt], 0, 0, 0);
            }
        }

        float sum = 0.f, sq = 0.f;
        #pragma unroll
        for (int nt = 0; nt < 6; ++nt) {
            f32x4 bv = *(const f32x4*)&prm[nt*16 + g*4];
            #pragma unroll
            for (int r = 0; r < 4; ++r) {
                float v = acc[nt][r] + bv[r];
                acc[nt][r] = v;
                sum += v;
                sq = fmaf(v, v, sq);
            }
        }
        sum += __shfl_xor(sum, 16); sum += __shfl_xor(sum, 32);
        sq  += __shfl_xor(sq, 16);  sq  += __shfl_xor(sq, 32);
        float muh = sum * (1.f/96.f);
        float rsh = rsqrtf(sq * (1.f/96.f) - muh*muh + 1e-5f);

        #pragma unroll
        for (int nt = 0; nt < 6; ++nt) {
            f32x4 gv  = *(const f32x4*)&prm[96  + nt*16 + g*4];
            f32x4 bev = *(const f32x4*)&prm[192 + nt*16 + g*4];
            float o0 = fmaf((acc[nt][0]-muh)*rsh, gv[0], bev[0]);
            float o1 = fmaf((acc[nt][1]-muh)*rsh, gv[1], bev[1]);
            float o2 = fmaf((acc[nt][2]-muh)*rsh, gv[2], bev[2]);
            float o3 = fmaf((acc[nt][3]-muh)*rsh, gv[3], bev[3]);
            uint2 st;
            st.x = bfr(o0) | (bfr(o1) << 16);
            st.y = bfr(o2) | (bfr(o3) << 16);
            int j0 = nt*16 + g*4;
            size_t q = (size_t)(nt*2 + (g >> 1));
            *(uint2*)((char*)h8 + (q*MM + slot)*16 + (size_t)(j0 & 7)*2) = st;
        }
    }
}

// ---------- kB: per-segment column max (double-buffered LDS staging) + zseg ----------
__global__ void __launch_bounds__(192) kB_seg(
    const uint4* __restrict__ h8,
    const unsigned* __restrict__ offs, const unsigned* __restrict__ scnt,
    const float* __restrict__ W3, const float* __restrict__ b3,
    float* __restrict__ segf, float* __restrict__ zseg)
{
    __shared__ uint4 st[2][16][13];
    __shared__ float lseg[96];
    int s = blockIdx.x, tid = threadIdx.x;
    unsigned cnt = scnt[s], off = offs[s];
    int r = tid & 15, q = tid >> 4;        // q < 12 for tid < 192
    float mx = -INFINITY;

    if (q < 12) {
        uint4 v = make_uint4(0xFF80FF80u, 0xFF80FF80u, 0xFF80FF80u, 0xFF80FF80u);
        if ((unsigned)r < cnt) v = h8[(size_t)q * MM + off + r];
        st[0][r][q] = v;
    }
    __syncthreads();

    for (unsigned base = 0; base < cnt; base += 16) {
        int cur = (int)((base >> 4) & 1u);
        unsigned nb = base + 16;
        if (nb < cnt && q < 12) {
            uint4 v = make_uint4(0xFF80FF80u, 0xFF80FF80u, 0xFF80FF80u, 0xFF80FF80u);
            if (nb + (unsigned)r < cnt) v = h8[(size_t)q * MM + off + nb + r];
            st[cur ^ 1][r][q] = v;
        }
        if (tid < 96) {
            int qj = tid >> 3, ej = tid & 7;
            #pragma unroll
            for (int rr = 0; rr < 16; ++rr) {
                const unsigned short* hp = (const unsigned short*)&st[cur][rr][qj];
                mx = fmaxf(mx, bf2f(hp[ej]));
            }
        }
        __syncthreads();
    }
    if (tid < 96) { segf[(size_t)s*96 + tid] = mx; lseg[tid] = mx; }
    __syncthreads();
    if (tid < 96) {
        float acc = b3[tid];
        #pragma unroll 4
        for (int i = 0; i < 96; ++i)
            acc = fmaf(lseg[i], W3[(size_t)(96+i)*96 + tid], acc);
        zseg[(size_t)s*96 + tid] = acc;
    }
}

// ---------- kC: MLP2 via MFMA (sorted streaming, prefetched) -> w ----------
__global__ void __launch_bounds__(256) kC_mfma(
    const uint4* __restrict__ h8, const float* __restrict__ zseg,
    const unsigned short* __restrict__ seg16, const unsigned* __restrict__ sorted,
    const float* __restrict__ W3, const float* __restrict__ g3,
    const float* __restrict__ be3, const float* __restrict__ W4,
    float* __restrict__ w_nat, float* __restrict__ w_srt)
{
    __shared__ unsigned short wT[96*WPAD];
    __shared__ float prm[3*96];
    int tid = threadIdx.x;
    #pragma unroll 4
    for (int it = 0; it < 36; ++it) {
        int e = it*256 + tid;
        int i = e / 96, j = e - i*96;
        wT[j*WPAD + i] = (unsigned short)bfr(W3[e]);   // W3a = first 96 rows
    }
    if (tid < 96) { prm[tid] = g3[tid]; prm[96+tid] = be3[tid]; prm[192+tid] = W4[tid]; }
    __syncthreads();

    int lane = tid & 63, w = tid >> 6;
    int pcol = lane & 15, g = lane >> 4;
    size_t slot0 = (size_t)blockIdx.x * 256 + w*64 + pcol;

    uint4 B0 = h8[(size_t)(0*4+g) * MM + slot0];
    uint4 B1 = h8[(size_t)(1*4+g) * MM + slot0];
    uint4 B2q = h8[(size_t)(2*4+g) * MM + slot0];

    #pragma unroll 1
    for (int t = 0; t < 4; ++t) {
        size_t slot = slot0 + (size_t)t * 16;
        uint4 C0 = B0, C1 = B1, C2 = B2q;
        if (t < 3) {
            size_t sn = slot + 16;
            C0 = h8[(size_t)(0*4+g) * MM + sn];
            C1 = h8[(size_t)(1*4+g) * MM + sn];
            C2 = h8[(size_t)(2*4+g) * MM + sn];
        }
        U4S8 u0, u1, u2; u0.u = B0; u1.u = B1; u2.u = B2q;
        short8 bB[3] = { u0.s, u1.s, u2.s };

        f32x4 acc[6];
        #pragma unroll
        for (int nt = 0; nt < 6; ++nt) acc[nt] = (f32x4){0.f,0.f,0.f,0.f};

        #pragma unroll
        for (int ks = 0; ks < 3; ++ks) {
            #pragma unroll
            for (int nt = 0; nt < 6; ++nt) {
                const short8 aF = *(const short8*)&wT[(nt*16 + pcol)*WPAD + ks*32 + g*8];
                acc[nt] = __builtin_amdgcn_mfma_f32_16x16x32_bf16(aF, bB[ks], acc[nt], 0, 0, 0);
            }
        }

        int s = seg16[slot];
        float sum = 0.f, sq = 0.f;
        #pragma unroll
        for (int nt = 0; nt < 6; ++nt) {
            f32x4 zs = *(const f32x4*)&zseg[(size_t)s*96 + nt*16 + g*4];
            #pragma unroll
            for (int r = 0; r < 4; ++r) {
                float v = acc[nt][r] + zs[r];
                acc[nt][r] = v;
                sum += v;
                sq = fmaf(v, v, sq);
            }
        }
        sum += __shfl_xor(sum, 16); sum += __shfl_xor(sum, 32);
        sq  += __shfl_xor(sq, 16);  sq  += __shfl_xor(sq, 32);
        float mu = sum * (1.f/96.f);
        float rs = rsqrtf(sq * (1.f/96.f) - mu*mu + 1e-5f);

        float tt = 0.f;
        #pragma unroll
        for (int nt = 0; nt < 6; ++nt) {
            f32x4 gv  = *(const f32x4*)&prm[nt*16 + g*4];
            f32x4 bev = *(const f32x4*)&prm[96 + nt*16 + g*4];
            f32x4 w4v = *(const f32x4*)&prm[192 + nt*16 + g*4];
            #pragma unroll
            for (int r = 0; r < 4; ++r) {
                float v = fmaxf(fmaf((acc[nt][r]-mu)*rs, gv[r], bev[r]), 0.f);
                tt = fmaf(v, w4v[r], tt);
            }
        }
        tt += __shfl_xor(tt, 16); tt += __shfl_xor(tt, 32);
        if (lane < 16) {
            float wv = 2.f / (1.f + expf(-tt));
            w_srt[slot] = wv;
            w_nat[sorted[slot]] = wv;
        }
        B0 = C0; B1 = C1; B2q = C2;
    }
}

// ---------- kD: per-segment weighted feat mean + seg (16-deep) ----------
__global__ void __launch_bounds__(128) kD_pool(
    const float* __restrict__ feat, const float* __restrict__ w_srt,
    const unsigned* __restrict__ sorted, const unsigned* __restrict__ offs,
    const unsigned* __restrict__ scnt, const float* __restrict__ segf,
    float* __restrict__ sp_out)
{
    int s = blockIdx.x;
    int c = threadIdx.x;
    unsigned cnt = scnt[s], off = offs[s];
    float acc = 0.f;
    unsigned r = 0;
    for (; r + 16 <= cnt; r += 16) {
        unsigned pp[16]; float ww[16];
        #pragma unroll
        for (int k = 0; k < 16; ++k) {
            pp[k] = sorted[off + r + k];
            ww[k] = w_srt[off + r + k];
        }
        if (c < 96) {
            #pragma unroll
            for (int k = 0; k < 16; ++k)
                acc = fmaf(feat[(size_t)pp[k]*96 + c], ww[k], acc);
        }
    }
    for (; r + 4 <= cnt; r += 4) {
        unsigned pp[4]; float ww[4];
        #pragma unroll
        for (int k = 0; k < 4; ++k) {
            pp[k] = sorted[off + r + k];
            ww[k] = w_srt[off + r + k];
        }
        if (c < 96) {
            #pragma unroll
            for (int k = 0; k < 4; ++k)
                acc = fmaf(feat[(size_t)pp[k]*96 + c], ww[k], acc);
        }
    }
    for (; r < cnt; ++r) {
        unsigned p0 = sorted[off + r];
        float w0 = w_srt[off + r];
        if (c < 96) acc = fmaf(feat[(size_t)p0*96 + c], w0, acc);
    }
    if (c < 96) {
        float cc = fmaxf((float)cnt, 1.f);
        sp_out[(size_t)s*96 + c] = acc / cc + segf[(size_t)s*96 + c];
    }
}

// ---------- launch ----------
extern "C" void kernel_launch(void* const* d_in, const int* in_sizes, int n_in,
                              void* d_out, int out_size, void* d_ws, size_t ws_size,
                              hipStream_t stream)
{
    const float* pts_feat = (const float*)d_in[0];
    const int*   sp_idx   = (const int*)d_in[1];
    const float* xyz      = (const float*)d_in[2];
    const float* W1  = (const float*)d_in[3];
    const float* b1  = (const float*)d_in[4];
    const float* g1  = (const float*)d_in[5];
    const float* be1 = (const float*)d_in[6];
    const float* W2  = (const float*)d_in[7];
    const float* b2  = (const float*)d_in[8];
    const float* g2  = (const float*)d_in[9];
    const float* be2 = (const float*)d_in[10];
    const float* W3  = (const float*)d_in[11];
    const float* b3  = (const float*)d_in[12];
    const float* g3  = (const float*)d_in[13];
    const float* be3 = (const float*)d_in[14];
    const float* W4  = (const float*)d_in[15];

    float* out = (float*)d_out;
    float* sp_out = out;                     // (B*K, 96)
    float* w_out  = out + (size_t)NSEG * 96; // (M,)

    if (ws_size < (size_t)WS_END * 4u) return;

    unsigned* ws32   = (unsigned*)d_ws;
    unsigned* scnt   = ws32 + WS_SCNT;
    unsigned* cursor = ws32 + WS_CURSOR;
    unsigned* offs   = ws32 + WS_OFFS;
    float*    m1     = (float*)(ws32 + WS_M1);
    float*    segf   = (float*)(ws32 + WS_SEGF);
    float*    zseg   = (float*)(ws32 + WS_ZSEG);
    unsigned* sorted = ws32 + WS_SORTED;
    unsigned short* seg16 = (unsigned short*)(ws32 + WS_SEG16);
    float*    w_srt  = (float*)(ws32 + WS_WSRT);
    uint4*    h8     = (uint4*)(ws32 + WS_H8);
    float*    pts    = (float*)(ws32 + WS_PTS);

    k0_init<<<32, 256, 0, stream>>>(ws32);
    k1_count<<<MM/4096, 256, 0, stream>>>(sp_idx, scnt);
    k2_scan<<<1, 1024, 0, stream>>>(scnt, offs, W1, b1, m1);
    k3_scatter<<<MM/4096, 256, 0, stream>>>(sp_idx, offs, cursor, sorted, seg16);
    k3b_stats<<<NSEG, 128, 0, stream>>>(xyz, sorted, offs, scnt, pts);
    kTA<<<MM/256, 256, 0, stream>>>(pts, W1, b1, g1, be1, m1,
        W2, b2, g2, be2, h8);
    kB_seg<<<NSEG, 192, 0, stream>>>(h8, offs, scnt, W3, b3, segf, zseg);
    kC_mfma<<<MM/256, 256, 0, stream>>>(h8, zseg, seg16, sorted, W3, g3, be3, W4,
        w_out, w_srt);
    kD_pool<<<NSEG, 128, 0, stream>>>(pts_feat, w_srt, sorted, offs, scnt, segf, sp_out);
}